// Round 3
// baseline (496.270 us; speedup 1.0000x reference)
//
#include <hip/hip_runtime.h>

typedef __attribute__((ext_vector_type(8))) short short8;
typedef __attribute__((ext_vector_type(4))) float f32x4;
typedef unsigned short ushort;
typedef unsigned int uint;

__device__ __forceinline__ float fast_exp2(float x) {
#if __has_builtin(__builtin_amdgcn_exp2f)
    return __builtin_amdgcn_exp2f(x);
#else
    return __expf(x * 0.6931471805599453f);
#endif
}
__device__ __forceinline__ float fast_rcp(float x) {
#if __has_builtin(__builtin_amdgcn_rcpf)
    return __builtin_amdgcn_rcpf(x);
#else
    return __frcp_rn(x);
#endif
}

// round-to-nearest-even f32 -> bf16 bits (used for We, one-time)
__device__ __forceinline__ ushort f2bf(float f) {
    uint x = __float_as_uint(f);
    x += 0x7fffu + ((x >> 16) & 1u);
    return (ushort)(x >> 16);
}

// cheap pack: round-half-up + v_perm_b32. dst lo16=bf16(x), hi16=bf16(y).
__device__ __forceinline__ uint pack2bf(float x, float y) {
    uint xi = __float_as_uint(x) + 0x8000u;
    uint yi = __float_as_uint(y) + 0x8000u;
    return __builtin_amdgcn_perm(yi, xi, 0x07060302u);
}

// 8 f32 -> short8 bf16 fragment (register-only)
__device__ __forceinline__ short8 pack8(float4 a, float4 b) {
    union { uint4 u; short8 s; } c;
    c.u.x = pack2bf(a.x, a.y);
    c.u.y = pack2bf(a.z, a.w);
    c.u.z = pack2bf(b.x, b.y);
    c.u.w = pack2bf(b.z, b.w);
    return c.s;
}

// -------- kernel 1 (merged prep):
// blocks 0..63:  Web = bf16(We)
// blocks 64..319: q_ws[b][o] = dot(query[b],Wq[o]) + bq[o] + be[o]
// block 320:     aux[0] = 8*(sum(Wv) + bv)
__global__ __launch_bounds__(256) void prep(
    const float* __restrict__ query, const float* __restrict__ Wq,
    const float* __restrict__ bq, const float* __restrict__ be,
    const float* __restrict__ We, const float* __restrict__ Wv,
    const float* __restrict__ bv, float* __restrict__ q_ws,
    ushort* __restrict__ Web, float* __restrict__ aux) {
    __shared__ float qrow[512];
    const int t = threadIdx.x;
    if (blockIdx.x < 64) {
        const int i = (blockIdx.x * 256 + t) * 4;
        float4 v = *(const float4*)(We + i);
        ushort4 u;
        u.x = f2bf(v.x); u.y = f2bf(v.y); u.z = f2bf(v.z); u.w = f2bf(v.w);
        *(ushort4*)(Web + i) = u;
        return;
    }
    if (blockIdx.x == 320) {
        if (t >= 64) return;
        float v = (t < 32) ? Wv[t] : 0.f;
#pragma unroll
        for (int off = 1; off < 32; off <<= 1) v += __shfl_xor(v, off, 64);
        if (t == 0) aux[0] = 8.f * (v + bv[0]);
        return;
    }
    const int b = blockIdx.x - 64;
    qrow[t]       = query[b * 512 + t];
    qrow[t + 256] = query[b * 512 + 256 + t];
    __syncthreads();
    const f32x4* wr = (const f32x4*)(Wq + (size_t)t * 512);
    float s0 = 0.f, s1 = 0.f, s2 = 0.f, s3 = 0.f;
#pragma unroll 8
    for (int j = 0; j < 128; j += 4) {
        f32x4 w0 = wr[j], w1 = wr[j + 1], w2 = wr[j + 2], w3 = wr[j + 3];
        f32x4 q0 = *(const f32x4*)(qrow + 4 * j);
        f32x4 q1 = *(const f32x4*)(qrow + 4 * j + 4);
        f32x4 q2 = *(const f32x4*)(qrow + 4 * j + 8);
        f32x4 q3 = *(const f32x4*)(qrow + 4 * j + 12);
        s0 += w0.x * q0.x + w0.y * q0.y + w0.z * q0.z + w0.w * q0.w;
        s1 += w1.x * q1.x + w1.y * q1.y + w1.z * q1.z + w1.w * q1.w;
        s2 += w2.x * q2.x + w2.y * q2.y + w2.z * q2.z + w2.w * q2.w;
        s3 += w3.x * q3.x + w3.y * q3.y + w3.z * q3.z + w3.w * q3.w;
    }
    q_ws[b * 256 + t] = (s0 + s1) + (s2 + s3) + bq[t] + be[t];
}

// -------- kernel 2: fused GEMM (e = ref@We^T) + tanh-scorer reduction
// BARRIER-FREE main loop. Wave (wr,wc) computes rows [row0+wr*32, +32) x
// cols [wc*128, +128). Key property: the A-fragment a lane needs for
// mfma_16x16x32 (row l&15 of the 16-row tile, cols (l>>4)*8 + k*32) is
// EXACTLY the 8 floats that lane loads itself -> A goes global->reg->
// pack->MFMA with no LDS, no barriers, no cross-wave exchange.
// Cost: Web read per wave (64 KB, L2-hot, ~1.07 GB aggregate L2 = ~31 us,
// under the 43 us HBM floor) and A rows read by both wc-waves (L1/L2
// absorbed, same CU). LDS use: 512 B epilogue scratch only.
#define BM 64

__global__ __launch_bounds__(256, 2) void fused_gemm(
    const float* __restrict__ ref, const ushort* __restrict__ Web,
    const float* __restrict__ q_ws, const float* __restrict__ Wv,
    const float* __restrict__ aux, float* __restrict__ out) {
    __shared__ float red[2][64];

    const int t = threadIdx.x;
    const int w = t >> 6;
    const int wr = w >> 1;      // row-group: rows row0 + wr*32 .. +31
    const int wc = w & 1;       // col-group: cols wc*128 .. +127
    const int l = t & 63;
    const int quad = l >> 4;    // 0..3
    const int lr = l & 15;
    const size_t row0 = (size_t)blockIdx.x * BM;
    const int b = (int)(row0 >> 10);

    const float* ap = ref + (row0 + wr * 32 + lr) * 256 + quad * 8;
    const ushort* Bp = Web + ((size_t)(wc * 128 + lr)) * 256 + quad * 8;

    // ---- B k=0 (L2-resident) issued first
    short8 bc[8];
#pragma unroll
    for (int cb = 0; cb < 8; ++cb)
        bc[cb] = *(const short8*)(Bp + cb * 16 * 256);

    // ---- A: global -> regs -> bf16 fragments, two halves (sched_barrier
    // bounds f32 liveness so the allocator can't hoist all 32 loads)
    short8 af[2][8];
#pragma unroll
    for (int k = 0; k < 4; ++k) {
        float4 a0 = *(const float4*)(ap + k * 32);
        float4 a1 = *(const float4*)(ap + k * 32 + 4);
        float4 a2 = *(const float4*)(ap + 16 * 256 + k * 32);
        float4 a3 = *(const float4*)(ap + 16 * 256 + k * 32 + 4);
        af[0][k] = pack8(a0, a1);
        af[1][k] = pack8(a2, a3);
    }
    __builtin_amdgcn_sched_barrier(0);
#pragma unroll
    for (int k = 4; k < 8; ++k) {
        float4 a0 = *(const float4*)(ap + k * 32);
        float4 a1 = *(const float4*)(ap + k * 32 + 4);
        float4 a2 = *(const float4*)(ap + 16 * 256 + k * 32);
        float4 a3 = *(const float4*)(ap + 16 * 256 + k * 32 + 4);
        af[0][k] = pack8(a0, a1);
        af[1][k] = pack8(a2, a3);
    }

    // ---- barrier-free K-loop, B one step ahead
    f32x4 acc[2][8];
#pragma unroll
    for (int i = 0; i < 2; ++i)
#pragma unroll
        for (int j = 0; j < 8; ++j) acc[i][j] = (f32x4){0.f, 0.f, 0.f, 0.f};

#pragma unroll
    for (int k = 0; k < 8; ++k) {
        short8 bn[8];
        if (k < 7) {
#pragma unroll
            for (int cb = 0; cb < 8; ++cb)
                bn[cb] = *(const short8*)(Bp + cb * 16 * 256 + (k + 1) * 32);
        }
#pragma unroll
        for (int rt = 0; rt < 2; ++rt)
#pragma unroll
            for (int cb = 0; cb < 8; ++cb)
                acc[rt][cb] = __builtin_amdgcn_mfma_f32_16x16x32_bf16(
                    af[rt][k], bc[cb], acc[rt][cb], 0, 0, 0);
        if (k < 7) {
#pragma unroll
            for (int cb = 0; cb < 8; ++cb) bc[cb] = bn[cb];
        }
    }

    // ---- epilogue: sum_n tanh(q+e)*Wv = const(aux) + sum_n w2*rcp(1+e^{2x})
    const float c2l = 2.885390081777927f;   // 2*log2(e)
    const float* qe = q_ws + b * 256 + wc * 128 + lr;
    const float w2a = -2.f * Wv[lr];
    const float w2b = -2.f * Wv[16 + lr];
    float qv[8];
#pragma unroll
    for (int cb = 0; cb < 8; ++cb) qv[cb] = qe[cb * 16] * c2l;

    float part[2][4];
#pragma unroll
    for (int rt = 0; rt < 2; ++rt)
#pragma unroll
        for (int r = 0; r < 4; ++r) part[rt][r] = 0.f;

#pragma unroll
    for (int cb = 0; cb < 8; ++cb) {
        const float w2 = (cb & 1) ? w2b : w2a;   // (n&31) = 16*(cb&1) + lr
#pragma unroll
        for (int rt = 0; rt < 2; ++rt)
#pragma unroll
            for (int r = 0; r < 4; ++r) {
                float e = fast_exp2(fmaf(acc[rt][cb][r], c2l, qv[cb]));
                part[rt][r] = fmaf(w2, fast_rcp(e + 1.f), part[rt][r]);
            }
    }
    // reduce across the 16 column-lanes (xor bits 0..3)
#pragma unroll
    for (int off = 1; off < 16; off <<= 1)
#pragma unroll
        for (int rt = 0; rt < 2; ++rt)
#pragma unroll
            for (int r = 0; r < 4; ++r)
                part[rt][r] += __shfl_xor(part[rt][r], off, 64);

    if (lr == 0) {
#pragma unroll
        for (int rt = 0; rt < 2; ++rt)
#pragma unroll
            for (int r = 0; r < 4; ++r)
                red[wc][wr * 32 + rt * 16 + quad * 4 + r] = part[rt][r];
    }
    __syncthreads();
    if (t < 64) {
        out[row0 + t] = red[0][t] + red[1][t] + aux[0];
    }
}

extern "C" void kernel_launch(void* const* d_in, const int* in_sizes, int n_in,
                              void* d_out, int out_size, void* d_ws, size_t ws_size,
                              hipStream_t stream) {
    const float* query = (const float*)d_in[0];
    const float* ref   = (const float*)d_in[1];
    const float* Wq    = (const float*)d_in[2];
    const float* bq    = (const float*)d_in[3];
    const float* We    = (const float*)d_in[4];
    const float* be    = (const float*)d_in[5];
    const float* Wv    = (const float*)d_in[6];
    const float* bv    = (const float*)d_in[7];
    float* out = (float*)d_out;

    float*  q_ws = (float*)d_ws;                                    // 256 KB
    ushort* Web  = (ushort*)((char*)d_ws + 262144);                 // 128 KB
    float*  aux  = (float*)((char*)d_ws + 262144 + 131072);         // 4 B

    prep<<<321, 256, 0, stream>>>(query, Wq, bq, be, We, Wv, bv, q_ws, Web, aux);
    fused_gemm<<<4096, 256, 0, stream>>>(ref, Web, q_ws, Wv, aux, out);
}

// Round 4
// 404.849 us; speedup vs baseline: 1.2258x; 1.2258x over previous
//
#include <hip/hip_runtime.h>

typedef __attribute__((ext_vector_type(8))) short short8;
typedef __attribute__((ext_vector_type(4))) float f32x4;
typedef unsigned short ushort;
typedef unsigned int uint;

__device__ __forceinline__ float fast_exp2(float x) {
#if __has_builtin(__builtin_amdgcn_exp2f)
    return __builtin_amdgcn_exp2f(x);
#else
    return __expf(x * 0.6931471805599453f);
#endif
}
__device__ __forceinline__ float fast_rcp(float x) {
#if __has_builtin(__builtin_amdgcn_rcpf)
    return __builtin_amdgcn_rcpf(x);
#else
    return __frcp_rn(x);
#endif
}

// round-to-nearest-even f32 -> bf16 bits (used for We, one-time)
__device__ __forceinline__ ushort f2bf(float f) {
    uint x = __float_as_uint(f);
    x += 0x7fffu + ((x >> 16) & 1u);
    return (ushort)(x >> 16);
}

// cheap pack: round-half-up + v_perm_b32. dst lo16=bf16(x), hi16=bf16(y).
__device__ __forceinline__ uint pack2bf(float x, float y) {
    uint xi = __float_as_uint(x) + 0x8000u;
    uint yi = __float_as_uint(y) + 0x8000u;
    return __builtin_amdgcn_perm(yi, xi, 0x07060302u);
}

// 8 f32 -> uint4 of 8 bf16 (register-only)
__device__ __forceinline__ uint4 pack8u(float4 a, float4 b) {
    uint4 c;
    c.x = pack2bf(a.x, a.y);
    c.y = pack2bf(a.z, a.w);
    c.z = pack2bf(b.x, b.y);
    c.w = pack2bf(b.z, b.w);
    return c;
}

// -------- kernel 1 (merged prep):
// blocks 0..63:  Web = bf16(We)
// blocks 64..319: q_ws[b][o] = dot(query[b],Wq[o]) + bq[o] + be[o]
// block 320:     aux[0] = 8*(sum(Wv) + bv)
__global__ __launch_bounds__(256) void prep(
    const float* __restrict__ query, const float* __restrict__ Wq,
    const float* __restrict__ bq, const float* __restrict__ be,
    const float* __restrict__ We, const float* __restrict__ Wv,
    const float* __restrict__ bv, float* __restrict__ q_ws,
    ushort* __restrict__ Web, float* __restrict__ aux) {
    __shared__ float qrow[512];
    const int t = threadIdx.x;
    if (blockIdx.x < 64) {
        const int i = (blockIdx.x * 256 + t) * 4;
        float4 v = *(const float4*)(We + i);
        ushort4 u;
        u.x = f2bf(v.x); u.y = f2bf(v.y); u.z = f2bf(v.z); u.w = f2bf(v.w);
        *(ushort4*)(Web + i) = u;
        return;
    }
    if (blockIdx.x == 320) {
        if (t >= 64) return;
        float v = (t < 32) ? Wv[t] : 0.f;
#pragma unroll
        for (int off = 1; off < 32; off <<= 1) v += __shfl_xor(v, off, 64);
        if (t == 0) aux[0] = 8.f * (v + bv[0]);
        return;
    }
    const int b = blockIdx.x - 64;
    qrow[t]       = query[b * 512 + t];
    qrow[t + 256] = query[b * 512 + 256 + t];
    __syncthreads();
    const f32x4* wr = (const f32x4*)(Wq + (size_t)t * 512);
    float s0 = 0.f, s1 = 0.f, s2 = 0.f, s3 = 0.f;
#pragma unroll 8
    for (int j = 0; j < 128; j += 4) {
        f32x4 w0 = wr[j], w1 = wr[j + 1], w2 = wr[j + 2], w3 = wr[j + 3];
        f32x4 q0 = *(const f32x4*)(qrow + 4 * j);
        f32x4 q1 = *(const f32x4*)(qrow + 4 * j + 4);
        f32x4 q2 = *(const f32x4*)(qrow + 4 * j + 8);
        f32x4 q3 = *(const f32x4*)(qrow + 4 * j + 12);
        s0 += w0.x * q0.x + w0.y * q0.y + w0.z * q0.z + w0.w * q0.w;
        s1 += w1.x * q1.x + w1.y * q1.y + w1.z * q1.z + w1.w * q1.w;
        s2 += w2.x * q2.x + w2.y * q2.y + w2.z * q2.z + w2.w * q2.w;
        s3 += w3.x * q3.x + w3.y * q3.y + w3.z * q3.z + w3.w * q3.w;
    }
    q_ws[b * 256 + t] = (s0 + s1) + (s2 + s3) + bq[t] + be[t];
}

// -------- kernel 2: persistent-B fused GEMM + tanh-scorer reduction.
// 512 blocks (exactly 2/CU), each owns 512 consecutive rows = 16 tiles of 32.
// B (Web strip, 32KB/wave) lives in 128 VGPRs for the whole block -> the
// K-loop has ZERO B memory traffic (kills the 1-deep-prefetch L2 stall that
// capped the old design at ~1.9 TB/s effective).
// A: double-buffered LDS (2 x 16KB fragment-slot layout); tile t+1's global
// loads issue BEFORE tile t's k-loop (full-compute-phase latency cover);
// barriers are lgkmcnt-only (global loads stay in flight across them).
// One barrier per tile; red and Asm double-buffered; out-store deferred one
// tile. Numerics identical to the round-0 kernel.
__global__ __launch_bounds__(256, 2) void fused_gemm(
    const float* __restrict__ ref, const ushort* __restrict__ Web,
    const float* __restrict__ q_ws, const float* __restrict__ Wv,
    const float* __restrict__ aux, float* __restrict__ out) {
    __shared__ uint4 Asm[2 * 1024];      // 2 buffers x 16KB (32 rows x 256 bf16)
    __shared__ float red[2][4][32];      // double-buffered cross-wave partials

    const int t = threadIdx.x;
    const int w = t >> 6;          // wave 0..3 -> compute col strip [64w,+64)
    const int l = t & 63;
    const int quad = l >> 4;       // 0..3
    const int lr = l & 15;
    const int rbw = w & 1;         // staging role: row-half 0/1
    const int kh = w >> 1;         // staging role: k-half 0/1
    const size_t rowB = (size_t)blockIdx.x * 512;   // block's first row
    const int b = (int)(blockIdx.x >> 1);           // batch fixed per block

    // ---- persistent B: 32 x short8 = 128 VGPR, loaded once (L2-hot)
    const ushort* Bp = Web + ((size_t)(w * 64 + lr)) * 256 + quad * 8;
    short8 bfr[4][8];
#pragma unroll
    for (int cb = 0; cb < 4; ++cb)
#pragma unroll
        for (int k = 0; k < 8; ++k)
            bfr[cb][k] = *(const short8*)(Bp + cb * 16 * 256 + k * 32);

    // ---- epilogue constants (hoisted: b fixed per block)
    const float c2l = 2.885390081777927f;   // 2*log2(e)
    const float* qe = q_ws + b * 256;
    const float w2a = -2.f * Wv[lr];
    const float w2b = -2.f * Wv[16 + lr];
    const float aux0 = aux[0];
    float qvc[4];
#pragma unroll
    for (int cb = 0; cb < 4; ++cb) qvc[cb] = qe[w * 64 + cb * 16 + lr] * c2l;

    // staging source: thread (rbw,kh,quad,lr) owns row rbw*16+lr,
    // cols quad*8 + (kh*4+kk)*32, kk=0..3  (fragment-slot exact match)
    const float* apst = ref + (rowB + rbw * 16 + lr) * 256 + kh * 128 + quad * 8;

    // ---- stage tile 0 into buffer 0
    {
        float4 f[8];
#pragma unroll
        for (int kk = 0; kk < 4; ++kk) {
            f[2 * kk]     = *(const float4*)(apst + kk * 32);
            f[2 * kk + 1] = *(const float4*)(apst + kk * 32 + 4);
        }
#pragma unroll
        for (int kk = 0; kk < 4; ++kk)
            Asm[(rbw * 8 + kh * 4 + kk) * 64 + l] = pack8u(f[2 * kk], f[2 * kk + 1]);
    }
    asm volatile("s_waitcnt lgkmcnt(0)" ::: "memory");
    __builtin_amdgcn_s_barrier();
    __builtin_amdgcn_sched_barrier(0);

    // ---- 16-tile main loop
    for (int tl = 0; tl < 16; ++tl) {
        const uint4* bufr = Asm + (tl & 1) * 1024;
        uint4* bufw = Asm + ((tl + 1) & 1) * 1024;

        // deferred out-store for tile tl-1 (safe: barrier(tl-1) ordered the
        // red writes; next write to this red parity is in tile tl+1)
        if (tl > 0 && t < 32) {
            const float* rp = &red[(tl - 1) & 1][0][0];
            out[rowB + (size_t)(tl - 1) * 32 + t] =
                rp[t] + rp[32 + t] + rp[64 + t] + rp[96 + t] + aux0;
        }

        // issue next tile's A loads FIRST (land under this tile's compute)
        float4 f[8];
        if (tl < 15) {
            const float* ap = apst + (size_t)(tl + 1) * 32 * 256;
#pragma unroll
            for (int kk = 0; kk < 4; ++kk) {
                f[2 * kk]     = *(const float4*)(ap + kk * 32);
                f[2 * kk + 1] = *(const float4*)(ap + kk * 32 + 4);
            }
        }

        // k-loop: 2 ds_read_b128 + 8 MFMA per k, B from registers
        f32x4 acc[2][4];
#pragma unroll
        for (int i = 0; i < 2; ++i)
#pragma unroll
            for (int j = 0; j < 4; ++j) acc[i][j] = (f32x4){0.f, 0.f, 0.f, 0.f};

        const ushort* As = (const ushort*)bufr;
#pragma unroll
        for (int k = 0; k < 8; ++k) {
            short8 afr[2];
#pragma unroll
            for (int rt = 0; rt < 2; ++rt)
                afr[rt] = *(const short8*)(As + ((rt * 8 + k) * 64 + l) * 8);
#pragma unroll
            for (int rt = 0; rt < 2; ++rt)
#pragma unroll
                for (int cb = 0; cb < 4; ++cb)
                    acc[rt][cb] = __builtin_amdgcn_mfma_f32_16x16x32_bf16(
                        afr[rt], bfr[cb][k], acc[rt][cb], 0, 0, 0);
        }

        // pack + write next tile into the other buffer
        if (tl < 15) {
#pragma unroll
            for (int kk = 0; kk < 4; ++kk)
                bufw[(rbw * 8 + kh * 4 + kk) * 64 + l] =
                    pack8u(f[2 * kk], f[2 * kk + 1]);
        }

        // epilogue: sum_n tanh(q+e)*Wv = const(aux) + sum_n w2*rcp(1+e^{2x})
        float part[2][4];
#pragma unroll
        for (int rt = 0; rt < 2; ++rt)
#pragma unroll
            for (int r = 0; r < 4; ++r) part[rt][r] = 0.f;
#pragma unroll
        for (int cb = 0; cb < 4; ++cb) {
            const float w2 = (cb & 1) ? w2b : w2a;   // (n&31)=16*(cb&1)+lr
#pragma unroll
            for (int rt = 0; rt < 2; ++rt)
#pragma unroll
                for (int r = 0; r < 4; ++r) {
                    float e = fast_exp2(fmaf(acc[rt][cb][r], c2l, qvc[cb]));
                    part[rt][r] = fmaf(w2, fast_rcp(e + 1.f), part[rt][r]);
                }
        }
#pragma unroll
        for (int off = 1; off < 16; off <<= 1)
#pragma unroll
            for (int rt = 0; rt < 2; ++rt)
#pragma unroll
                for (int r = 0; r < 4; ++r)
                    part[rt][r] += __shfl_xor(part[rt][r], off, 64);
        if (lr == 0) {
#pragma unroll
            for (int rt = 0; rt < 2; ++rt)
#pragma unroll
                for (int r = 0; r < 4; ++r)
                    red[tl & 1][w][rt * 16 + quad * 4 + r] = part[rt][r];
        }

        // single per-tile barrier: LDS-only drain, global loads stay in flight
        asm volatile("s_waitcnt lgkmcnt(0)" ::: "memory");
        __builtin_amdgcn_s_barrier();
        __builtin_amdgcn_sched_barrier(0);
    }

    // final tile's output
    if (t < 32) {
        const float* rp = &red[15 & 1][0][0];
        out[rowB + 15 * 32 + t] =
            rp[t] + rp[32 + t] + rp[64 + t] + rp[96 + t] + aux0;
    }
}

extern "C" void kernel_launch(void* const* d_in, const int* in_sizes, int n_in,
                              void* d_out, int out_size, void* d_ws, size_t ws_size,
                              hipStream_t stream) {
    const float* query = (const float*)d_in[0];
    const float* ref   = (const float*)d_in[1];
    const float* Wq    = (const float*)d_in[2];
    const float* bq    = (const float*)d_in[3];
    const float* We    = (const float*)d_in[4];
    const float* be    = (const float*)d_in[5];
    const float* Wv    = (const float*)d_in[6];
    const float* bv    = (const float*)d_in[7];
    float* out = (float*)d_out;

    float*  q_ws = (float*)d_ws;                                    // 256 KB
    ushort* Web  = (ushort*)((char*)d_ws + 262144);                 // 128 KB
    float*  aux  = (float*)((char*)d_ws + 262144 + 131072);         // 4 B

    prep<<<321, 256, 0, stream>>>(query, Wq, bq, be, We, Wv, bv, q_ws, Web, aux);
    fused_gemm<<<512, 256, 0, stream>>>(ref, Web, q_ws, Wv, aux, out);
}